// Round 12
// baseline (1236.374 us; speedup 1.0000x reference)
//
#include <hip/hip_runtime.h>
#include <stdint.h>

// Problem constants (reference: EMB=256, HID=1024, N_TRACKS=4096, SEQ=9, n_predict=12)
#define NTRK 4096
#define HIDN 1024
#define EMBN 256
#define KTOT 1280   // EMB + HID
#define NOUT 19     // 8 enc + 11 dec steps

typedef __attribute__((ext_vector_type(8))) short short8;
typedef __attribute__((ext_vector_type(4))) float f32x4;

typedef __attribute__((address_space(1))) const void GV;
typedef __attribute__((address_space(3))) void LV;

__device__ __forceinline__ uint16_t f2bf(float f) {
  uint32_t u = __float_as_uint(f);
  u += 0x7fffu + ((u >> 16) & 1u);   // round-to-nearest-even
  return (uint16_t)(u >> 16);
}
__device__ __forceinline__ float bf2f(uint16_t v) {
  return __uint_as_float(((uint32_t)v) << 16);
}
// precise (setup only)
__device__ __forceinline__ float sigm(float x) { return 1.0f / (1.0f + expf(-x)); }
// fast (hot paths): v_exp + v_rcp; error ~1e-6, margin is 5.5x
__device__ __forceinline__ float sigmf_(float x) {
  return __builtin_amdgcn_rcpf(1.0f + __expf(-x));
}
__device__ __forceinline__ float tanhf_(float x) {
  return 2.0f * __builtin_amdgcn_rcpf(1.0f + __expf(-2.0f * x)) - 1.0f;
}

// -------------------------------------------------------------------------
// Weight prep (16-unit gate groups): permuted row j' = q*64 + gate*16 + u16
// maps to original row gate*1024 + (q*16+u16). A 64-wide N-slab holds the
// 4 gates (i,f,g,o) of 16 hidden units -> LSTM pointwise is lane-local.
// Wih|Whh concatenated into one [4096][1280] bf16 row (single stride).
// -------------------------------------------------------------------------
__global__ __launch_bounds__(256) void prep_weights(
    const float* __restrict__ encWih, const float* __restrict__ encWhh,
    const float* __restrict__ encB,
    const float* __restrict__ decWih, const float* __restrict__ decWhh,
    const float* __restrict__ decB,
    uint16_t* __restrict__ WcatE, uint16_t* __restrict__ WcatD,
    float* __restrict__ biasE, float* __restrict__ biasD, float* __restrict__ biasDT)
{
  const int jp = blockIdx.x;                 // permuted row 0..4095
  const int q = jp >> 6, r = jp & 63;
  const int gate = r >> 4, l16 = r & 15;
  const int u = q * 16 + l16;
  const int orig = gate * 1024 + u;
  const int t = threadIdx.x;                 // 0..255

  WcatE[(size_t)jp * KTOT + t] = f2bf(encWih[(size_t)orig * 256 + t]);
  WcatD[(size_t)jp * KTOT + t] = f2bf(decWih[(size_t)orig * 256 + t]);
#pragma unroll
  for (int c = 0; c < 4; c++) {
    WcatE[(size_t)jp * KTOT + 256 + c * 256 + t] = f2bf(encWhh[(size_t)orig * 1024 + c * 256 + t]);
    WcatD[(size_t)jp * KTOT + 256 + c * 256 + t] = f2bf(decWhh[(size_t)orig * 1024 + c * 256 + t]);
  }
  if (t == 0) {
    biasE[jp]  = encB[orig];
    biasD[jp]  = decB[orig];
    biasDT[jp] = decB[orig] + decWih[(size_t)orig * 256 + 255]; // dec tag one-hot col 255
  }
}

// Enc-tag cell with h=c=0: gates identical for all tracks -> closed form.
__global__ void init_h0(const float* __restrict__ encWih, const float* __restrict__ encB,
                        float* __restrict__ h0, float* __restrict__ c0)
{
  const int u = blockIdx.x * 256 + threadIdx.x;   // 0..1023
  if (u >= 1024) return;
  const float gi = encWih[(size_t)(u) * 256 + 254]        + encB[u];
  const float gg = encWih[(size_t)(2048 + u) * 256 + 254] + encB[2048 + u];
  const float go = encWih[(size_t)(3072 + u) * 256 + 254] + encB[3072 + u];
  const float c = sigm(gi) * tanhf(gg);   // sigm(gf)*0 + ...
  c0[u] = c;
  h0[u] = sigm(go) * tanhf(c);
}

// t=0 rank-1 fold: every track starts from the SAME h0, so H@Whh^T at step 0
// is row-constant. biasE0[jp] = encB[orig] + dot(h0, encWhh[orig][:]).
// One wave per permuted row; f32 throughout (setup precision).
__global__ __launch_bounds__(256) void bias_h0(
    const float* __restrict__ encWhh, const float* __restrict__ encB,
    const float* __restrict__ h0, float* __restrict__ biasE0)
{
  const int jp = blockIdx.x * 4 + (threadIdx.x >> 6);   // 0..4095
  const int lane = threadIdx.x & 63;
  const int q = jp >> 6, r = jp & 63;
  const int gate = r >> 4, l16 = r & 15;
  const int orig = gate * 1024 + (q * 16 + l16);
  const float* wr = encWhh + (size_t)orig * 1024 + lane * 16;
  const float* hr = h0 + lane * 16;
  float s = 0.f;
#pragma unroll
  for (int e = 0; e < 16; e++) s += wr[e] * hr[e];
  s += __shfl_xor(s, 32); s += __shfl_xor(s, 16); s += __shfl_xor(s, 8);
  s += __shfl_xor(s, 4);  s += __shfl_xor(s, 2);  s += __shfl_xor(s, 1);
  if (lane == 0) biasE0[jp] = encB[orig] + s;
}

// embed fallback for one encoder step (if workspace can't hold Xall)
__global__ __launch_bounds__(256) void embed_k(
    const float* __restrict__ o1, const float* __restrict__ o2,
    const float* __restrict__ ew, const float* __restrict__ eb,
    uint16_t* __restrict__ X)
{
  const int trk = blockIdx.x;
  const int j = threadIdx.x;
  const float vx = (o2[trk * 2]     - o1[trk * 2])     * 4.0f;
  const float vy = (o2[trk * 2 + 1] - o1[trk * 2 + 1]) * 4.0f;
  float e = 0.f;
  if (j < 254) e = fmaxf(vx * ew[j * 2] + vy * ew[j * 2 + 1] + eb[j], 0.f);
  X[(size_t)trk * 256 + j] = f2bf(e);
}

// All 8 encoder embeds in one dispatch (inputs known upfront).
__global__ __launch_bounds__(256) void embed8(
    const float* __restrict__ observed, const float* __restrict__ ew,
    const float* __restrict__ eb, uint16_t* __restrict__ Xall)
{
  const int t = blockIdx.y;          // 0..7
  const int trk = blockIdx.x;
  const int j = threadIdx.x;
  const float* o1 = observed + ((size_t)t * 4096 + trk) * 2;
  const float* o2 = o1 + 4096 * 2;
  const float vx = (o2[0] - o1[0]) * 4.0f;
  const float vy = (o2[1] - o1[1]) * 4.0f;
  float e = 0.f;
  if (j < 254) e = fmaxf(vx * ew[j * 2] + vy * ew[j * 2 + 1] + eb[j], 0.f);
  Xall[((size_t)t * 4096 + trk) * 256 + j] = f2bf(e);
}

// -------------------------------------------------------------------------
// Fused LSTM-cell GEMM — R12 = R9/R11 hot structure (measured stable at
// 53.8-54.0us, MfmaUtil ~31, conflicts 0, 2 blocks/CU) with:
//  - stagger removed (R11: falsified, null)
//  - initmode: t=0 epilogue reads c0/h0 broadcast instead of Cst/Hin and
//    writes Cst=c0 for frozen rows -> fill_state kernel eliminated
//    (25MB writes + 1 dispatch saved; bit-identical math).
// Structure recap (R7-verified): 128x256 block, 8 waves of 64x64, BK=32,
// ring-3 LDS (A 3x8KB + B 3x16KB = 72KB), counted vmcnt(3) cadence
// (stage T+2 at top of T; vmcnt(3) retires T+1; drain only last 2 tiles),
// swizzle LDS(r,c)=G(r,c^((r>>1)&3)), XCD map 16bm x 4bn per XCD
// (2.56MB weight panel L2-resident across all 20 steps).
// R8 lesson kept: A must stay LDS-staged (per-lane global frags = 64-seg
// gather, 2x regression). R10 lesson: ring-4 pre-read restructure = 2x
// regression. 10-round record: this is the 2-phase-class plateau (794 TF
// ~= 94% of m248's full-stack 848 TF at comparable K, incl. LSTM epilogue).
// -------------------------------------------------------------------------
__global__ __launch_bounds__(512, 4) void gemm_lstm(
    const uint16_t* __restrict__ X,    const uint16_t* __restrict__ Hin,
    const uint16_t* __restrict__ Wcat, const float* __restrict__ bias,
    float* __restrict__ Cst,           uint16_t* __restrict__ Hout,
    const float* __restrict__ obs1,    const float* __restrict__ obs2,
    const float* __restrict__ h0v,     const float* __restrict__ c0v,
    int k0, int kend, int maskmode, int initmode)
{
  __shared__ uint16_t As[3 * 4096];   // 3 ring slots x [128 rows][32 k] = 24KB
  __shared__ uint16_t Bs[3 * 8192];   // 3 ring slots x [256 rows][32 k] = 48KB
  __shared__ uint8_t  smask[128];

  const int tid  = threadIdx.x;
  const int w    = tid >> 6;          // wave 0..7
  const int lane = tid & 63;
  const int wr   = w >> 2;            // 0..1 : M half (64 rows)
  const int wc   = w & 3;             // 0..3 : N slab (64 cols = 4 gates x 16 units)
  const int quad = lane >> 4;
  const int l15  = lane & 15;

  // XCD-bijective mapping: 512 blocks = 8 XCDs x 64; per XCD 16 bm x 4 bn.
  const int bid = blockIdx.y * 16 + blockIdx.x;
  const int xcd = bid & 7;
  const int j   = bid >> 3;           // 0..63
  const int bmS = (xcd >> 2) * 16 + (j >> 2);   // 0..31
  const int bnS = (xcd & 3) * 4 + (j & 3);      // 0..15
  const int bm  = bmS * 128;          // track rows
  const int bn  = bnS * 256;          // permuted gate cols

  const int NT = (kend - k0) >> 5;    // 40 / 32 (tag) / 8 (t=0)

  if (tid < 128) {
    bool m = true;
    if (maskmode) {
      const float a = obs1[(bm + tid) * 2];
      const float b = obs2[(bm + tid) * 2];
      m = !((a != a) || (b != b));
    }
    smask[tid] = m ? 1 : 0;
  }

  // Staging: one gload_lds (all 8 waves) covers 128 rows x 32k (8KB).
  // Wave w, lane l -> row w*16 + (l>>2), 16B chunk (l&3); source chunk
  // pre-swizzled: chunk_g = (l&3) ^ ((l>>3)&3) so LDS(r,c)=G(r,c^((r>>1)&3)).
  const int srow = w * 16 + (lane >> 2);
  const int sch  = ((lane & 3) ^ ((lane >> 3) & 3)) * 8;   // elements
  const uint16_t* pXr = X ? X + (size_t)(bm + srow) * 256 + sch : (const uint16_t*)0;
  const uint16_t* pHr = Hin  + (size_t)(bm + srow) * 1024 + sch;
  const uint16_t* pWr = Wcat + (size_t)(bn + srow) * (size_t)KTOT + sch;

  auto stage = [&](int V, int slot) {   // 3 gload_lds: A(128), B h0(128), B h1(128)
    if (V >= NT) return;
    const int kg = k0 + V * 32;
    uint16_t* ad = As + slot * 4096 + w * 16 * 32;
    if (kg < 256) {
      __builtin_amdgcn_global_load_lds((GV*)(pXr + kg),         (LV*)ad, 16, 0, 0);
    } else {
      __builtin_amdgcn_global_load_lds((GV*)(pHr + (kg - 256)), (LV*)ad, 16, 0, 0);
    }
    uint16_t* bd = Bs + slot * 8192 + w * 16 * 32;
    __builtin_amdgcn_global_load_lds((GV*)(pWr + kg),                        (LV*)bd,          16, 0, 0);
    __builtin_amdgcn_global_load_lds((GV*)(pWr + (size_t)128 * KTOT + kg),   (LV*)(bd + 4096), 16, 0, 0);
  };

  f32x4 acc[4][4];   // [Mfrag][gate] — 64 VGPR
#pragma unroll
  for (int i = 0; i < 4; i++)
#pragma unroll
    for (int n = 0; n < 4; n++) acc[i][n] = (f32x4){0.f, 0.f, 0.f, 0.f};

  // prologue: stage tiles 0,1 (6 loads); land tile 0, keep tile 1 in flight
  stage(0, 0); stage(1, 1);
  asm volatile("s_waitcnt vmcnt(3)" ::: "memory");
  __builtin_amdgcn_s_barrier();

  // fragment read chunk: G-chunk quad at row l15 -> LDS chunk quad^((l15>>1)&3)
  const int cc = (quad ^ ((l15 >> 1) & 3)) * 8;   // elements

  int sT = 0;                          // T % 3
  for (int T = 0; T < NT; T++) {
    const int sS = (sT == 0) ? 2 : sT - 1;   // (T+2) % 3 == (T-1) % 3
    const uint16_t* Ab = As + sT * 4096;
    const uint16_t* Bb = Bs + sT * 8192;
    short8 a[4], b[4];
#pragma unroll
    for (int i = 0; i < 4; i++)
      a[i] = *(const short8*)(Ab + (wr * 64 + i * 16 + l15) * 32 + cc);
#pragma unroll
    for (int n = 0; n < 4; n++)
      b[n] = *(const short8*)(Bb + (wc * 64 + n * 16 + l15) * 32 + cc);
    stage(T + 2, sS);
    __builtin_amdgcn_s_setprio(1);
#pragma unroll
    for (int i = 0; i < 4; i++)
#pragma unroll
      for (int n = 0; n < 4; n++)
        acc[i][n] = __builtin_amdgcn_mfma_f32_16x16x32_bf16(a[i], b[n], acc[i][n], 0, 0, 0);
    __builtin_amdgcn_s_setprio(0);
    if (T < NT - 2) {
      asm volatile("s_waitcnt vmcnt(3)" ::: "memory");   // tile T+1 landed; T+2 in flight
    } else {
      asm volatile("s_waitcnt vmcnt(0)" ::: "memory");   // tail (loads 2 tiles stale)
    }
    __builtin_amdgcn_s_barrier();
    sT = (sT == 2) ? 0 : sT + 1;
  }

  // Epilogue: wave rows = bm + wr*64 + i*16 + quad*4 + r; cols = gate slab wc.
  // C/D layout: col = lane&15, row = quad*4 + reg  [m89-verified]
  // initmode: state comes from h0/c0 broadcast (fill_state folded in here).
  const int u  = ((bn >> 6) + wc) * 16 + l15;
  const int jb = bn + wc * 64 + l15;
  const float b_i = bias[jb];
  const float b_f = bias[jb + 16];
  const float b_g = bias[jb + 32];
  const float b_o = bias[jb + 48];
  const float c0u = initmode ? c0v[u] : 0.f;
  const uint16_t h0u = initmode ? f2bf(h0v[u]) : (uint16_t)0;

#pragma unroll
  for (int i = 0; i < 4; i++) {
#pragma unroll
    for (int r = 0; r < 4; r++) {
      const int row = bm + wr * 64 + i * 16 + quad * 4 + r;
      const size_t idx = (size_t)row * 1024 + u;
      uint16_t hv;
      if (smask[row - bm]) {
        const float cprev = initmode ? c0u : Cst[idx];
        const float gi = acc[i][0][r] + b_i;
        const float gf = acc[i][1][r] + b_f;
        const float gg = acc[i][2][r] + b_g;
        const float go = acc[i][3][r] + b_o;
        const float cn = sigmf_(gf) * cprev + sigmf_(gi) * tanhf_(gg);
        Cst[idx] = cn;
        hv = f2bf(sigmf_(go) * tanhf_(cn));
      } else if (initmode) {
        Cst[idx] = c0u;       // frozen row still needs its state initialized
        hv = h0u;
      } else {
        hv = Hin[idx];        // state frozen; Hout is a different buffer
      }
      Hout[idx] = hv;
    }
  }
}

// -------------------------------------------------------------------------
// h2n + outputs (+ optional fused embed for the NEXT step's X):
// raw = h @ h2n_w.T + h2n_b (one wave per track). Butterfly reduce leaves the
// full sums in ALL lanes; lane0 writes outputs; all lanes embed next X.
// -------------------------------------------------------------------------
__global__ __launch_bounds__(256) void h2n_pos(
    const uint16_t* __restrict__ H, const float* __restrict__ w5, const float* __restrict__ b5,
    const float* __restrict__ obs1, const float* __restrict__ obs2,
    float* __restrict__ outrel, float* __restrict__ outpos,
    const float* __restrict__ pprev, const float* __restrict__ ew,
    const float* __restrict__ eb, uint16_t* __restrict__ Xnext, int do_embed)
{
  const int lane  = threadIdx.x & 63;
  const int track = blockIdx.x * 4 + (threadIdx.x >> 6);

  const uint16_t* hrow = H + (size_t)track * 1024 + lane * 16;
  const short8 v0 = *(const short8*)(hrow);
  const short8 v1 = *(const short8*)(hrow + 8);
  float hv[16];
#pragma unroll
  for (int j = 0; j < 8; j++) {
    hv[j]     = bf2f((uint16_t)v0[j]);
    hv[8 + j] = bf2f((uint16_t)v1[j]);
  }
  const int kb = lane * 16;
  float p[5];
#pragma unroll
  for (int o = 0; o < 5; o++) {
    const float* wr = w5 + (size_t)o * 1024 + kb;
    float s = 0.f;
#pragma unroll
    for (int j = 0; j < 16; j++) s += hv[j] * wr[j];
    p[o] = s;
  }
#pragma unroll
  for (int o = 0; o < 5; o++) {
    float v = p[o];
    v += __shfl_xor(v, 32); v += __shfl_xor(v, 16); v += __shfl_xor(v, 8);
    v += __shfl_xor(v, 4);  v += __shfl_xor(v, 2);  v += __shfl_xor(v, 1);
    p[o] = v;
  }
  // all lanes hold the full sums now
  const float o1x = obs1[track * 2];
  const float o2x = obs2[track * 2];
  const float o2y = obs2[track * 2 + 1];
  const bool msk = !((o1x != o1x) || (o2x != o2x));
  float n0 = p[0] + b5[0];
  float n1 = p[1] + b5[1];
  float n2 = 0.01f + 0.2f * sigmf_(p[2] + b5[2]);
  float n3 = 0.01f + 0.2f * sigmf_(p[3] + b5[3]);
  float n4 = 0.7f  * sigmf_(p[4] + b5[4]);
  if (!msk) {
    const float qn = __uint_as_float(0x7fc00000u);
    n0 = n1 = n2 = n3 = n4 = qn;
  }
  const float posx = o2x + n0;
  const float posy = o2y + n1;
  if (lane == 0) {
    float* rr = outrel + (size_t)track * 5;
    rr[0] = n0; rr[1] = n1; rr[2] = n2; rr[3] = n3; rr[4] = n4;
    outpos[track * 2]     = posx;
    outpos[track * 2 + 1] = posy;
  }
  if (do_embed) {
    const float vx = (posx - pprev[track * 2])     * 4.0f;
    const float vy = (posy - pprev[track * 2 + 1]) * 4.0f;
    uint16_t* xr = Xnext + (size_t)track * 256;
#pragma unroll
    for (int ii = 0; ii < 4; ii++) {
      const int j = ii * 64 + lane;
      float e = 0.f;
      if (j < 254) e = fmaxf(vx * ew[j * 2] + vy * ew[j * 2 + 1] + eb[j], 0.f);
      xr[j] = f2bf(e);   // NaN inputs -> fmax gives 0; row is masked anyway
    }
  }
}

// -------------------------------------------------------------------------
extern "C" void kernel_launch(void* const* d_in, const int* in_sizes, int n_in,
                              void* d_out, int out_size, void* d_ws, size_t ws_size,
                              hipStream_t stream)
{
  const float* observed = (const float*)d_in[0];
  const float* emb_w    = (const float*)d_in[1];
  const float* emb_b    = (const float*)d_in[2];
  const float* enc_wih  = (const float*)d_in[3];
  const float* enc_whh  = (const float*)d_in[4];
  const float* enc_b    = (const float*)d_in[5];
  const float* dec_wih  = (const float*)d_in[6];
  const float* dec_whh  = (const float*)d_in[7];
  const float* dec_b    = (const float*)d_in[8];
  const float* h2n_w    = (const float*)d_in[9];
  const float* h2n_b    = (const float*)d_in[10];
  // d_in[11] = n_predict (==12, fixed by setup)

  char* ws = (char*)d_ws;
  size_t off = 0;
  auto alloc = [&](size_t bytes) -> void* {
    size_t cur = (off + 255) & ~(size_t)255;
    off = cur + bytes;
    return (void*)(ws + cur);
  };
  uint16_t* WcatE = (uint16_t*)alloc((size_t)4096 * KTOT * 2);
  uint16_t* WcatD = (uint16_t*)alloc((size_t)4096 * KTOT * 2);
  float*    biasE = (float*)alloc(4096 * 4);
  float*    biasE0= (float*)alloc(4096 * 4);
  float*    biasD = (float*)alloc(4096 * 4);
  float*    biasDT= (float*)alloc(4096 * 4);
  float*    h0    = (float*)alloc(1024 * 4);
  float*    c0    = (float*)alloc(1024 * 4);
  uint16_t* HA    = (uint16_t*)alloc((size_t)4096 * 1024 * 2);
  uint16_t* HB    = (uint16_t*)alloc((size_t)4096 * 1024 * 2);
  float*    Cst   = (float*)alloc((size_t)4096 * 1024 * 4);
  uint16_t* Xb    = (uint16_t*)alloc((size_t)4096 * 256 * 2);
  // optional batched encoder X (16 MB) — only if workspace allows
  const size_t xall_bytes = (size_t)8 * 4096 * 256 * 2;
  const bool use_xall = (off + 256 + xall_bytes) <= ws_size;
  uint16_t* Xall = use_xall ? (uint16_t*)alloc(xall_bytes) : nullptr;

  float* outrel = (float*)d_out;                     // (19, 4096, 5)
  float* outpos = outrel + (size_t)NOUT * 4096 * 5;  // (19, 4096, 2)

  prep_weights<<<4096, 256, 0, stream>>>(enc_wih, enc_whh, enc_b, dec_wih, dec_whh, dec_b,
                                         WcatE, WcatD, biasE, biasD, biasDT);
  init_h0<<<4, 256, 0, stream>>>(enc_wih, enc_b, h0, c0);
  bias_h0<<<1024, 256, 0, stream>>>(enc_whh, enc_b, h0, biasE0);
  if (use_xall) {
    embed8<<<dim3(4096, 8), 256, 0, stream>>>(observed, emb_w, emb_b, Xall);
  }

  uint16_t* Hin = HA;
  uint16_t* Hout = HB;
  const dim3 ggrid(16, 32);   // 512 blocks = 32 bm x 16 bn tiles (128x256)

  // ---- encoder: 8 steps over observed pairs ----
  for (int t = 0; t < 8; t++) {
    const float* o1 = observed + (size_t)t * 4096 * 2;
    const float* o2 = observed + (size_t)(t + 1) * 4096 * 2;
    uint16_t* Xt = Xb;
    if (use_xall) {
      Xt = Xall + (size_t)t * 4096 * 256;
    } else {
      embed_k<<<4096, 256, 0, stream>>>(o1, o2, emb_w, emb_b, Xb);
    }
    if (t == 0) {
      // rank-1 H-part folded into biasE0; initmode folds fill_state in
      gemm_lstm<<<ggrid, 512, 0, stream>>>(Xt, Hin, WcatE, biasE0, Cst, Hout, o1, o2,
                                           h0, c0, 0, 256, 1, 1);
    } else {
      gemm_lstm<<<ggrid, 512, 0, stream>>>(Xt, Hin, WcatE, biasE, Cst, Hout, o1, o2,
                                           nullptr, nullptr, 0, KTOT, 1, 0);
    }
    const int de = (t == 7) ? 1 : 0;   // t==7 also embeds X for first decoder step
    h2n_pos<<<1024, 256, 0, stream>>>(Hout, h2n_w, h2n_b, o1, o2,
                                      outrel + (size_t)t * 4096 * 5,
                                      outpos + (size_t)t * 4096 * 2,
                                      outpos + (size_t)6 * 4096 * 2, emb_w, emb_b, Xb, de);
    uint16_t* tmp = Hin; Hin = Hout; Hout = tmp;
  }

  // ---- decoder tag cell (x one-hot folded into biasDT; k0=256 skips X) ----
  gemm_lstm<<<ggrid, 512, 0, stream>>>(nullptr, Hin, WcatD, biasDT, Cst, Hout,
                                       nullptr, nullptr, nullptr, nullptr, 256, KTOT, 0, 0);
  { uint16_t* tmp = Hin; Hin = Hout; Hout = tmp; }

  // ---- decoder: 11 steps; X comes from the previous step's fused h2n ----
  for (int s = 0; s < 11; s++) {
    const float* p1 = outpos + (size_t)(6 + s) * 4096 * 2;
    const float* p2 = outpos + (size_t)(7 + s) * 4096 * 2;
    gemm_lstm<<<ggrid, 512, 0, stream>>>(Xb, Hin, WcatD, biasD, Cst, Hout, p1, p2,
                                         nullptr, nullptr, 0, KTOT, 1, 0);
    const int de = (s < 10) ? 1 : 0;   // last step needs no next X
    h2n_pos<<<1024, 256, 0, stream>>>(Hout, h2n_w, h2n_b, p1, p2,
                                      outrel + (size_t)(8 + s) * 4096 * 5,
                                      outpos + (size_t)(8 + s) * 4096 * 2,
                                      p2, emb_w, emb_b, Xb, de);
    uint16_t* tmp = Hin; Hin = Hout; Hout = tmp;
  }
}

// Round 13
// 1184.355 us; speedup vs baseline: 1.0439x; 1.0439x over previous
//
#include <hip/hip_runtime.h>
#include <stdint.h>

// Problem constants (reference: EMB=256, HID=1024, N_TRACKS=4096, SEQ=9, n_predict=12)
#define NTRK 4096
#define HIDN 1024
#define EMBN 256
#define KTOT 1280   // EMB + HID
#define NOUT 19     // 8 enc + 11 dec steps

typedef __attribute__((ext_vector_type(8))) short short8;
typedef __attribute__((ext_vector_type(4))) float f32x4;

typedef __attribute__((address_space(1))) const void GV;
typedef __attribute__((address_space(3))) void LV;

__device__ __forceinline__ uint16_t f2bf(float f) {
  uint32_t u = __float_as_uint(f);
  u += 0x7fffu + ((u >> 16) & 1u);   // round-to-nearest-even
  return (uint16_t)(u >> 16);
}
__device__ __forceinline__ float bf2f(uint16_t v) {
  return __uint_as_float(((uint32_t)v) << 16);
}
// precise (setup only)
__device__ __forceinline__ float sigm(float x) { return 1.0f / (1.0f + expf(-x)); }
// fast (hot paths): v_exp + v_rcp; error ~1e-6, margin is 5.5x
__device__ __forceinline__ float sigmf_(float x) {
  return __builtin_amdgcn_rcpf(1.0f + __expf(-x));
}
__device__ __forceinline__ float tanhf_(float x) {
  return 2.0f * __builtin_amdgcn_rcpf(1.0f + __expf(-2.0f * x)) - 1.0f;
}

// -------------------------------------------------------------------------
// Weight prep (16-unit gate groups): permuted row j' = q*64 + gate*16 + u16
// maps to original row gate*1024 + (q*16+u16). A 64-wide N-slab holds the
// 4 gates (i,f,g,o) of 16 hidden units -> LSTM pointwise is lane-local.
// Wih|Whh concatenated into one [4096][1280] bf16 row (single stride).
// -------------------------------------------------------------------------
__global__ __launch_bounds__(256) void prep_weights(
    const float* __restrict__ encWih, const float* __restrict__ encWhh,
    const float* __restrict__ encB,
    const float* __restrict__ decWih, const float* __restrict__ decWhh,
    const float* __restrict__ decB,
    uint16_t* __restrict__ WcatE, uint16_t* __restrict__ WcatD,
    float* __restrict__ biasE, float* __restrict__ biasD, float* __restrict__ biasDT)
{
  const int jp = blockIdx.x;                 // permuted row 0..4095
  const int q = jp >> 6, r = jp & 63;
  const int gate = r >> 4, l16 = r & 15;
  const int u = q * 16 + l16;
  const int orig = gate * 1024 + u;
  const int t = threadIdx.x;                 // 0..255

  WcatE[(size_t)jp * KTOT + t] = f2bf(encWih[(size_t)orig * 256 + t]);
  WcatD[(size_t)jp * KTOT + t] = f2bf(decWih[(size_t)orig * 256 + t]);
#pragma unroll
  for (int c = 0; c < 4; c++) {
    WcatE[(size_t)jp * KTOT + 256 + c * 256 + t] = f2bf(encWhh[(size_t)orig * 1024 + c * 256 + t]);
    WcatD[(size_t)jp * KTOT + 256 + c * 256 + t] = f2bf(decWhh[(size_t)orig * 1024 + c * 256 + t]);
  }
  if (t == 0) {
    biasE[jp]  = encB[orig];
    biasD[jp]  = decB[orig];
    biasDT[jp] = decB[orig] + decWih[(size_t)orig * 256 + 255]; // dec tag one-hot col 255
  }
}

// Enc-tag cell with h=c=0: gates identical for all tracks -> closed form.
__global__ void init_h0(const float* __restrict__ encWih, const float* __restrict__ encB,
                        float* __restrict__ h0, float* __restrict__ c0)
{
  const int u = blockIdx.x * 256 + threadIdx.x;   // 0..1023
  if (u >= 1024) return;
  const float gi = encWih[(size_t)(u) * 256 + 254]        + encB[u];
  const float gg = encWih[(size_t)(2048 + u) * 256 + 254] + encB[2048 + u];
  const float go = encWih[(size_t)(3072 + u) * 256 + 254] + encB[3072 + u];
  const float c = sigm(gi) * tanhf(gg);   // sigm(gf)*0 + ...
  c0[u] = c;
  h0[u] = sigm(go) * tanhf(c);
}

// t=0 rank-1 fold: every track starts from the SAME h0, so H@Whh^T at step 0
// is row-constant. biasE0[jp] = encB[orig] + dot(h0, encWhh[orig][:]).
__global__ __launch_bounds__(256) void bias_h0(
    const float* __restrict__ encWhh, const float* __restrict__ encB,
    const float* __restrict__ h0, float* __restrict__ biasE0)
{
  const int jp = blockIdx.x * 4 + (threadIdx.x >> 6);   // 0..4095
  const int lane = threadIdx.x & 63;
  const int q = jp >> 6, r = jp & 63;
  const int gate = r >> 4, l16 = r & 15;
  const int orig = gate * 1024 + (q * 16 + l16);
  const float* wr = encWhh + (size_t)orig * 1024 + lane * 16;
  const float* hr = h0 + lane * 16;
  float s = 0.f;
#pragma unroll
  for (int e = 0; e < 16; e++) s += wr[e] * hr[e];
  s += __shfl_xor(s, 32); s += __shfl_xor(s, 16); s += __shfl_xor(s, 8);
  s += __shfl_xor(s, 4);  s += __shfl_xor(s, 2);  s += __shfl_xor(s, 1);
  if (lane == 0) biasE0[jp] = encB[orig] + s;
}

// embed fallback for one encoder step (if workspace can't hold Xall)
__global__ __launch_bounds__(256) void embed_k(
    const float* __restrict__ o1, const float* __restrict__ o2,
    const float* __restrict__ ew, const float* __restrict__ eb,
    uint16_t* __restrict__ X)
{
  const int trk = blockIdx.x;
  const int j = threadIdx.x;
  const float vx = (o2[trk * 2]     - o1[trk * 2])     * 4.0f;
  const float vy = (o2[trk * 2 + 1] - o1[trk * 2 + 1]) * 4.0f;
  float e = 0.f;
  if (j < 254) e = fmaxf(vx * ew[j * 2] + vy * ew[j * 2 + 1] + eb[j], 0.f);
  X[(size_t)trk * 256 + j] = f2bf(e);
}

// All 8 encoder embeds in one dispatch (inputs known upfront).
__global__ __launch_bounds__(256) void embed8(
    const float* __restrict__ observed, const float* __restrict__ ew,
    const float* __restrict__ eb, uint16_t* __restrict__ Xall)
{
  const int t = blockIdx.y;          // 0..7
  const int trk = blockIdx.x;
  const int j = threadIdx.x;
  const float* o1 = observed + ((size_t)t * 4096 + trk) * 2;
  const float* o2 = o1 + 4096 * 2;
  const float vx = (o2[0] - o1[0]) * 4.0f;
  const float vy = (o2[1] - o1[1]) * 4.0f;
  float e = 0.f;
  if (j < 254) e = fmaxf(vx * ew[j * 2] + vy * ew[j * 2 + 1] + eb[j], 0.f);
  Xall[((size_t)t * 4096 + trk) * 256 + j] = f2bf(e);
}

// -------------------------------------------------------------------------
// h2n body (shared by standalone kernel and gemm piggyback): one wave per
// track. Butterfly reduce leaves the full sums in ALL lanes; lane0 writes
// outputs; all lanes embed next X when do_embed.
// -------------------------------------------------------------------------
__device__ __forceinline__ void h2n_body(
    int track, int lane,
    const uint16_t* __restrict__ H, const float* __restrict__ w5, const float* __restrict__ b5,
    const float* __restrict__ obs1, const float* __restrict__ obs2,
    float* __restrict__ outrel, float* __restrict__ outpos,
    const float* __restrict__ pprev, const float* __restrict__ ew,
    const float* __restrict__ eb, uint16_t* __restrict__ Xnext, int do_embed)
{
  const uint16_t* hrow = H + (size_t)track * 1024 + lane * 16;
  const short8 v0 = *(const short8*)(hrow);
  const short8 v1 = *(const short8*)(hrow + 8);
  float hv[16];
#pragma unroll
  for (int j = 0; j < 8; j++) {
    hv[j]     = bf2f((uint16_t)v0[j]);
    hv[8 + j] = bf2f((uint16_t)v1[j]);
  }
  const int kb = lane * 16;
  float p[5];
#pragma unroll
  for (int o = 0; o < 5; o++) {
    const float* wr = w5 + (size_t)o * 1024 + kb;
    float s = 0.f;
#pragma unroll
    for (int j = 0; j < 16; j++) s += hv[j] * wr[j];
    p[o] = s;
  }
#pragma unroll
  for (int o = 0; o < 5; o++) {
    float v = p[o];
    v += __shfl_xor(v, 32); v += __shfl_xor(v, 16); v += __shfl_xor(v, 8);
    v += __shfl_xor(v, 4);  v += __shfl_xor(v, 2);  v += __shfl_xor(v, 1);
    p[o] = v;
  }
  const float o1x = obs1[track * 2];
  const float o2x = obs2[track * 2];
  const float o2y = obs2[track * 2 + 1];
  const bool msk = !((o1x != o1x) || (o2x != o2x));
  float n0 = p[0] + b5[0];
  float n1 = p[1] + b5[1];
  float n2 = 0.01f + 0.2f * sigmf_(p[2] + b5[2]);
  float n3 = 0.01f + 0.2f * sigmf_(p[3] + b5[3]);
  float n4 = 0.7f  * sigmf_(p[4] + b5[4]);
  if (!msk) {
    const float qn = __uint_as_float(0x7fc00000u);
    n0 = n1 = n2 = n3 = n4 = qn;
  }
  const float posx = o2x + n0;
  const float posy = o2y + n1;
  if (lane == 0) {
    float* rr = outrel + (size_t)track * 5;
    rr[0] = n0; rr[1] = n1; rr[2] = n2; rr[3] = n3; rr[4] = n4;
    outpos[track * 2]     = posx;
    outpos[track * 2 + 1] = posy;
  }
  if (do_embed) {
    const float vx = (posx - pprev[track * 2])     * 4.0f;
    const float vy = (posy - pprev[track * 2 + 1]) * 4.0f;
    uint16_t* xr = Xnext + (size_t)track * 256;
#pragma unroll
    for (int ii = 0; ii < 4; ii++) {
      const int j = ii * 64 + lane;
      float e = 0.f;
      if (j < 254) e = fmaxf(vx * ew[j * 2] + vy * ew[j * 2 + 1] + eb[j], 0.f);
      xr[j] = f2bf(e);   // NaN inputs -> fmax gives 0; row is masked anyway
    }
  }
}

// -------------------------------------------------------------------------
// Fused LSTM-cell GEMM — R13 = R12 hot structure (measured stable at
// ~54-55us, MfmaUtil ~30, conflicts 0, 2 blocks/CU) + PIGGYBACK h2n:
// blocks with blockIdx.y >= 32 run the PREVIOUS step's h2n (8 tracks per
// 512-thread block, 512 blocks). Legal because encoder gemm(t+1) reads
// nothing h2n(t) produces: h2n(t) reads Hin of this dispatch (shared,
// stable input) + observed; writes outrel/outpos(t), first consumed by
// the decoder mask many dispatches later. Same for h2n(7) on the tag
// gemm (tag skips X, so its Xb write races nothing). Decoder h2n stays
// standalone (its embed feeds the NEXT gemm - true serial dep).
// Gemm blocks have lower linear block IDs -> scheduled first; the short
// h2n blocks backfill retiring CUs -> 8 dispatches + gaps absorbed.
// Structure recap (R7-verified): 128x256 block, 8 waves of 64x64, BK=32,
// ring-3 LDS (72KB), counted vmcnt(3) cadence, swizzle
// LDS(r,c)=G(r,c^((r>>1)&3)), XCD map 16bm x 4bn per XCD, initmode folds
// fill_state (R12), rank-1 t=0 fold (R9). R8/R10 lessons: A stays
// LDS-staged; no ring-4 pre-read.
// -------------------------------------------------------------------------
__global__ __launch_bounds__(512, 4) void gemm_lstm(
    const uint16_t* __restrict__ X,    const uint16_t* __restrict__ Hin,
    const uint16_t* __restrict__ Wcat, const float* __restrict__ bias,
    float* __restrict__ Cst,           uint16_t* __restrict__ Hout,
    const float* __restrict__ obs1,    const float* __restrict__ obs2,
    const float* __restrict__ h0v,     const float* __restrict__ c0v,
    int k0, int kend, int maskmode, int initmode,
    // piggyback h2n of the previous step (blocks with blockIdx.y >= 32):
    const uint16_t* __restrict__ phH,  const float* __restrict__ w5,
    const float* __restrict__ b5,
    const float* __restrict__ ph_o1,   const float* __restrict__ ph_o2,
    float* __restrict__ ph_rel,        float* __restrict__ ph_pos,
    const float* __restrict__ ph_prev, const float* __restrict__ ew,
    const float* __restrict__ eb,      uint16_t* __restrict__ ph_Xn,
    int ph_embed)
{
  __shared__ uint16_t As[3 * 4096];   // 3 ring slots x [128 rows][32 k] = 24KB
  __shared__ uint16_t Bs[3 * 8192];   // 3 ring slots x [256 rows][32 k] = 48KB
  __shared__ uint8_t  smask[128];

  const int tid  = threadIdx.x;

  if (blockIdx.y >= 32) {             // ---- piggyback h2n path ----
    const int pb = (blockIdx.y - 32) * 16 + blockIdx.x;   // 0..511
    const int track = pb * 8 + (tid >> 6);
    h2n_body(track, tid & 63, phH, w5, b5, ph_o1, ph_o2,
             ph_rel, ph_pos, ph_prev, ew, eb, ph_Xn, ph_embed);
    return;                            // before any barrier (block-uniform)
  }

  const int w    = tid >> 6;          // wave 0..7
  const int lane = tid & 63;
  const int wr   = w >> 2;            // 0..1 : M half (64 rows)
  const int wc   = w & 3;             // 0..3 : N slab (64 cols = 4 gates x 16 units)
  const int quad = lane >> 4;
  const int l15  = lane & 15;

  // XCD-bijective mapping: 512 gemm blocks = 8 XCDs x 64; per XCD 16 bm x 4 bn.
  const int bid = blockIdx.y * 16 + blockIdx.x;
  const int xcd = bid & 7;
  const int j   = bid >> 3;           // 0..63
  const int bmS = (xcd >> 2) * 16 + (j >> 2);   // 0..31
  const int bnS = (xcd & 3) * 4 + (j & 3);      // 0..15
  const int bm  = bmS * 128;          // track rows
  const int bn  = bnS * 256;          // permuted gate cols

  const int NT = (kend - k0) >> 5;    // 40 / 32 (tag) / 8 (t=0)

  if (tid < 128) {
    bool m = true;
    if (maskmode) {
      const float a = obs1[(bm + tid) * 2];
      const float b = obs2[(bm + tid) * 2];
      m = !((a != a) || (b != b));
    }
    smask[tid] = m ? 1 : 0;
  }

  // Staging: one gload_lds (all 8 waves) covers 128 rows x 32k (8KB).
  // Wave w, lane l -> row w*16 + (l>>2), 16B chunk (l&3); source chunk
  // pre-swizzled: chunk_g = (l&3) ^ ((l>>3)&3) so LDS(r,c)=G(r,c^((r>>1)&3)).
  const int srow = w * 16 + (lane >> 2);
  const int sch  = ((lane & 3) ^ ((lane >> 3) & 3)) * 8;   // elements
  const uint16_t* pXr = X ? X + (size_t)(bm + srow) * 256 + sch : (const uint16_t*)0;
  const uint16_t* pHr = Hin  + (size_t)(bm + srow) * 1024 + sch;
  const uint16_t* pWr = Wcat + (size_t)(bn + srow) * (size_t)KTOT + sch;

  auto stage = [&](int V, int slot) {   // 3 gload_lds: A(128), B h0(128), B h1(128)
    if (V >= NT) return;
    const int kg = k0 + V * 32;
    uint16_t* ad = As + slot * 4096 + w * 16 * 32;
    if (kg < 256) {
      __builtin_amdgcn_global_load_lds((GV*)(pXr + kg),         (LV*)ad, 16, 0, 0);
    } else {
      __builtin_amdgcn_global_load_lds((GV*)(pHr + (kg - 256)), (LV*)ad, 16, 0, 0);
    }
    uint16_t* bd = Bs + slot * 8192 + w * 16 * 32;
    __builtin_amdgcn_global_load_lds((GV*)(pWr + kg),                        (LV*)bd,          16, 0, 0);
    __builtin_amdgcn_global_load_lds((GV*)(pWr + (size_t)128 * KTOT + kg),   (LV*)(bd + 4096), 16, 0, 0);
  };

  f32x4 acc[4][4];   // [Mfrag][gate] — 64 VGPR
#pragma unroll
  for (int i = 0; i < 4; i++)
#pragma unroll
    for (int n = 0; n < 4; n++) acc[i][n] = (f32x4){0.f, 0.f, 0.f, 0.f};

  // prologue: stage tiles 0,1 (6 loads); land tile 0, keep tile 1 in flight
  stage(0, 0); stage(1, 1);
  asm volatile("s_waitcnt vmcnt(3)" ::: "memory");
  __builtin_amdgcn_s_barrier();

  // fragment read chunk: G-chunk quad at row l15 -> LDS chunk quad^((l15>>1)&3)
  const int cc = (quad ^ ((l15 >> 1) & 3)) * 8;   // elements

  int sT = 0;                          // T % 3
  for (int T = 0; T < NT; T++) {
    const int sS = (sT == 0) ? 2 : sT - 1;   // (T+2) % 3 == (T-1) % 3
    const uint16_t* Ab = As + sT * 4096;
    const uint16_t* Bb = Bs + sT * 8192;
    short8 a[4], b[4];
#pragma unroll
    for (int i = 0; i < 4; i++)
      a[i] = *(const short8*)(Ab + (wr * 64 + i * 16 + l15) * 32 + cc);
#pragma unroll
    for (int n = 0; n < 4; n++)
      b[n] = *(const short8*)(Bb + (wc * 64 + n * 16 + l15) * 32 + cc);
    stage(T + 2, sS);
    __builtin_amdgcn_s_setprio(1);
#pragma unroll
    for (int i = 0; i < 4; i++)
#pragma unroll
      for (int n = 0; n < 4; n++)
        acc[i][n] = __builtin_amdgcn_mfma_f32_16x16x32_bf16(a[i], b[n], acc[i][n], 0, 0, 0);
    __builtin_amdgcn_s_setprio(0);
    if (T < NT - 2) {
      asm volatile("s_waitcnt vmcnt(3)" ::: "memory");   // tile T+1 landed; T+2 in flight
    } else {
      asm volatile("s_waitcnt vmcnt(0)" ::: "memory");   // tail (loads 2 tiles stale)
    }
    __builtin_amdgcn_s_barrier();
    sT = (sT == 2) ? 0 : sT + 1;
  }

  // Epilogue: wave rows = bm + wr*64 + i*16 + quad*4 + r; cols = gate slab wc.
  // C/D layout: col = lane&15, row = quad*4 + reg  [m89-verified]
  // initmode: state comes from h0/c0 broadcast (fill_state folded in here).
  const int u  = ((bn >> 6) + wc) * 16 + l15;
  const int jb = bn + wc * 64 + l15;
  const float b_i = bias[jb];
  const float b_f = bias[jb + 16];
  const float b_g = bias[jb + 32];
  const float b_o = bias[jb + 48];
  const float c0u = initmode ? c0v[u] : 0.f;
  const uint16_t h0u = initmode ? f2bf(h0v[u]) : (uint16_t)0;

#pragma unroll
  for (int i = 0; i < 4; i++) {
#pragma unroll
    for (int r = 0; r < 4; r++) {
      const int row = bm + wr * 64 + i * 16 + quad * 4 + r;
      const size_t idx = (size_t)row * 1024 + u;
      uint16_t hv;
      if (smask[row - bm]) {
        const float cprev = initmode ? c0u : Cst[idx];
        const float gi = acc[i][0][r] + b_i;
        const float gf = acc[i][1][r] + b_f;
        const float gg = acc[i][2][r] + b_g;
        const float go = acc[i][3][r] + b_o;
        const float cn = sigmf_(gf) * cprev + sigmf_(gi) * tanhf_(gg);
        Cst[idx] = cn;
        hv = f2bf(sigmf_(go) * tanhf_(cn));
      } else if (initmode) {
        Cst[idx] = c0u;       // frozen row still needs its state initialized
        hv = h0u;
      } else {
        hv = Hin[idx];        // state frozen; Hout is a different buffer
      }
      Hout[idx] = hv;
    }
  }
}

// -------------------------------------------------------------------------
// standalone h2n (decoder steps — embed feeds the NEXT gemm, so it cannot
// piggyback). 4 tracks per 256-thread block.
// -------------------------------------------------------------------------
__global__ __launch_bounds__(256) void h2n_pos(
    const uint16_t* __restrict__ H, const float* __restrict__ w5, const float* __restrict__ b5,
    const float* __restrict__ obs1, const float* __restrict__ obs2,
    float* __restrict__ outrel, float* __restrict__ outpos,
    const float* __restrict__ pprev, const float* __restrict__ ew,
    const float* __restrict__ eb, uint16_t* __restrict__ Xnext, int do_embed)
{
  const int lane  = threadIdx.x & 63;
  const int track = blockIdx.x * 4 + (threadIdx.x >> 6);
  h2n_body(track, lane, H, w5, b5, obs1, obs2, outrel, outpos,
           pprev, ew, eb, Xnext, do_embed);
}

// -------------------------------------------------------------------------
extern "C" void kernel_launch(void* const* d_in, const int* in_sizes, int n_in,
                              void* d_out, int out_size, void* d_ws, size_t ws_size,
                              hipStream_t stream)
{
  const float* observed = (const float*)d_in[0];
  const float* emb_w    = (const float*)d_in[1];
  const float* emb_b    = (const float*)d_in[2];
  const float* enc_wih  = (const float*)d_in[3];
  const float* enc_whh  = (const float*)d_in[4];
  const float* enc_b    = (const float*)d_in[5];
  const float* dec_wih  = (const float*)d_in[6];
  const float* dec_whh  = (const float*)d_in[7];
  const float* dec_b    = (const float*)d_in[8];
  const float* h2n_w    = (const float*)d_in[9];
  const float* h2n_b    = (const float*)d_in[10];
  // d_in[11] = n_predict (==12, fixed by setup)

  char* ws = (char*)d_ws;
  size_t off = 0;
  auto alloc = [&](size_t bytes) -> void* {
    size_t cur = (off + 255) & ~(size_t)255;
    off = cur + bytes;
    return (void*)(ws + cur);
  };
  uint16_t* WcatE = (uint16_t*)alloc((size_t)4096 * KTOT * 2);
  uint16_t* WcatD = (uint16_t*)alloc((size_t)4096 * KTOT * 2);
  float*    biasE = (float*)alloc(4096 * 4);
  float*    biasE0= (float*)alloc(4096 * 4);
  float*    biasD = (float*)alloc(4096 * 4);
  float*    biasDT= (float*)alloc(4096 * 4);
  float*    h0    = (float*)alloc(1024 * 4);
  float*    c0    = (float*)alloc(1024 * 4);
  uint16_t* HA    = (uint16_t*)alloc((size_t)4096 * 1024 * 2);
  uint16_t* HB    = (uint16_t*)alloc((size_t)4096 * 1024 * 2);
  float*    Cst   = (float*)alloc((size_t)4096 * 1024 * 4);
  uint16_t* Xb    = (uint16_t*)alloc((size_t)4096 * 256 * 2);
  // optional batched encoder X (16 MB) — only if workspace allows
  const size_t xall_bytes = (size_t)8 * 4096 * 256 * 2;
  const bool use_xall = (off + 256 + xall_bytes) <= ws_size;
  uint16_t* Xall = use_xall ? (uint16_t*)alloc(xall_bytes) : nullptr;

  float* outrel = (float*)d_out;                     // (19, 4096, 5)
  float* outpos = outrel + (size_t)NOUT * 4096 * 5;  // (19, 4096, 2)

  prep_weights<<<4096, 256, 0, stream>>>(enc_wih, enc_whh, enc_b, dec_wih, dec_whh, dec_b,
                                         WcatE, WcatD, biasE, biasD, biasDT);
  init_h0<<<4, 256, 0, stream>>>(enc_wih, enc_b, h0, c0);
  bias_h0<<<1024, 256, 0, stream>>>(enc_whh, enc_b, h0, biasE0);
  if (use_xall) {
    embed8<<<dim3(4096, 8), 256, 0, stream>>>(observed, emb_w, emb_b, Xall);
  }

  uint16_t* Hin = HA;
  uint16_t* Hout = HB;
  const dim3 ggrid(16, 32);    // 512 gemm blocks (no piggyback)
  const dim3 pgrid(16, 64);    // + 512 piggyback h2n blocks

  // ---- encoder: 8 gemm dispatches; t>=1 piggybacks h2n(t-1) ----
  for (int t = 0; t < 8; t++) {
    const float* o1 = observed + (size_t)t * 4096 * 2;
    const float* o2 = observed + (size_t)(t + 1) * 4096 * 2;
    uint16_t* Xt = Xb;
    if (use_xall) {
      Xt = Xall + (size_t)t * 4096 * 256;
    } else {
      embed_k<<<4096, 256, 0, stream>>>(o1, o2, emb_w, emb_b, Xb);
    }
    if (t == 0) {
      // rank-1 H-part folded into biasE0; initmode folds fill_state in
      gemm_lstm<<<ggrid, 512, 0, stream>>>(Xt, Hin, WcatE, biasE0, Cst, Hout, o1, o2,
                                           h0, c0, 0, 256, 1, 1,
                                           nullptr, nullptr, nullptr, nullptr, nullptr,
                                           nullptr, nullptr, nullptr, nullptr, nullptr,
                                           nullptr, 0);
    } else {
      // piggyback h2n(t-1): reads Hin (this dispatch's stable input) +
      // observed(t-1); writes outrel/outpos(t-1) (first consumed by the
      // decoder mask, many dispatches later). No embed (only t-1==7 embeds).
      const float* po1 = observed + (size_t)(t - 1) * 4096 * 2;
      const float* po2 = observed + (size_t)t * 4096 * 2;
      gemm_lstm<<<pgrid, 512, 0, stream>>>(Xt, Hin, WcatE, biasE, Cst, Hout, o1, o2,
                                           nullptr, nullptr, 0, KTOT, 1, 0,
                                           Hin, h2n_w, h2n_b, po1, po2,
                                           outrel + (size_t)(t - 1) * 4096 * 5,
                                           outpos + (size_t)(t - 1) * 4096 * 2,
                                           nullptr, emb_w, emb_b, nullptr, 0);
    }
    uint16_t* tmp = Hin; Hin = Hout; Hout = tmp;
  }

  // ---- decoder tag cell: piggybacks h2n(7) WITH embed (tag skips X, so
  // the Xb write races nothing; decoder s=0 reads Xb next dispatch) ----
  gemm_lstm<<<pgrid, 512, 0, stream>>>(nullptr, Hin, WcatD, biasDT, Cst, Hout,
                                       nullptr, nullptr, nullptr, nullptr, 256, KTOT, 0, 0,
                                       Hin, h2n_w, h2n_b,
                                       observed + (size_t)7 * 4096 * 2,
                                       observed + (size_t)8 * 4096 * 2,
                                       outrel + (size_t)7 * 4096 * 5,
                                       outpos + (size_t)7 * 4096 * 2,
                                       outpos + (size_t)6 * 4096 * 2,
                                       emb_w, emb_b, Xb, 1);
  { uint16_t* tmp = Hin; Hin = Hout; Hout = tmp; }

  // ---- decoder: 11 steps; h2n stays standalone (embed feeds next gemm) ----
  for (int s = 0; s < 11; s++) {
    const float* p1 = outpos + (size_t)(6 + s) * 4096 * 2;
    const float* p2 = outpos + (size_t)(7 + s) * 4096 * 2;
    gemm_lstm<<<ggrid, 512, 0, stream>>>(Xb, Hin, WcatD, biasD, Cst, Hout, p1, p2,
                                         nullptr, nullptr, 0, KTOT, 1, 0,
                                         nullptr, nullptr, nullptr, nullptr, nullptr,
                                         nullptr, nullptr, nullptr, nullptr, nullptr,
                                         nullptr, 0);
    const int de = (s < 10) ? 1 : 0;   // last step needs no next X
    h2n_pos<<<1024, 256, 0, stream>>>(Hout, h2n_w, h2n_b, p1, p2,
                                      outrel + (size_t)(8 + s) * 4096 * 5,
                                      outpos + (size_t)(8 + s) * 4096 * 2,
                                      p2, emb_w, emb_b, Xb, de);
    uint16_t* tmp = Hin; Hin = Hout; Hout = tmp;
  }
}